// Round 24
// baseline (876.026 us; speedup 1.0000x reference)
//
#include <hip/hip_runtime.h>

#define N_NODES 50000
#define E_ADJ   800000
#define E_DEC   200000
#define FDIM    128
#define HDIM    64
#define NP1     (N_NODES + 1)
#define NBUK    196            // ceil(50000/256) buckets of 256 rows
#define SUBS    32             // sub-counters per bucket (blockIdx & 31)
#define SCAP    192            // per-sub capacity (mean 127.5, +5.7 sigma)
#define BCAP    (SUBS * SCAP)  // 6144 per bucket
#define TILE_E  1024           // edges per part-block (R20 TLP win kept)
#define EPB     4              // edges per thread
#define NPBLK   782            // ceil(E_ADJ/TILE_E)
#define COLH    25000          // column split point (table half = 3.2MB < 4MB L2)

typedef _Float16 f16;
typedef __attribute__((ext_vector_type(2))) _Float16 f16x2;
typedef __attribute__((ext_vector_type(4))) _Float16 f16x4;
typedef __attribute__((ext_vector_type(8))) _Float16 f16x8;
typedef __attribute__((ext_vector_type(4))) float f32x4;

__device__ __forceinline__ int      ntl_i(const int* p)      { return __builtin_nontemporal_load(p); }
__device__ __forceinline__ float    ntl_f(const float* p)    { return __builtin_nontemporal_load(p); }
__device__ __forceinline__ unsigned ntl_u(const unsigned* p) { return __builtin_nontemporal_load(p); }

// ---------------------------------------------------------------------------
// CSR build. part_kernel = R20 (TILE_E 1024). bucket_sort R24: sort key =
// (row_local, col>=COLH) and emit mid[k][n] so gathers can run as two
// column-half passes with an L2-resident table (R23 FETCH=105MB == exact
// zero-reuse: 800k x 128B; slice 6.4MB > 4MB L2 -> split to 3.2MB halves).
// ---------------------------------------------------------------------------
__global__ void part_kernel(const int* __restrict__ rows,
                            const int* __restrict__ cols,
                            const float* __restrict__ vals,
                            int* __restrict__ gcur,            // [4][NBUK][SUBS]
                            unsigned long long* __restrict__ bucketed)
{
    const int k   = blockIdx.y;
    const int sub = blockIdx.x & (SUBS - 1);
    const int tid = threadIdx.x;
    const long long t0 = (long long)blockIdx.x * TILE_E;

    __shared__ int hist[NBUK];
    __shared__ int cur[NBUK];
    for (int i = tid; i < NBUK; i += 256) hist[i] = 0;
    __syncthreads();

    for (int it = 0; it < EPB; ++it) {
        const long long e = t0 + it * 256 + tid;
        if (e < E_ADJ) {
            const int r = rows[(size_t)k * E_ADJ + e];
            atomicAdd(&hist[r >> 8], 1);
        }
    }
    __syncthreads();

    for (int i = tid; i < NBUK; i += 256)
        cur[i] = (hist[i] > 0) ? atomicAdd(&gcur[(k * NBUK + i) * SUBS + sub], hist[i]) : 0;
    __syncthreads();

    for (int it = 0; it < EPB; ++it) {
        const long long e = t0 + it * 256 + tid;
        if (e < E_ADJ) {
            const int r = rows[(size_t)k * E_ADJ + e];
            const int b = r >> 8;
            const int pos = atomicAdd(&cur[b], 1);
            const int c = ntl_i(&cols[(size_t)k * E_ADJ + e]);
            const float v = ntl_f(&vals[(size_t)k * E_ADJ + e]);
            const unsigned meta = (unsigned)c | ((unsigned)(r & 255) << 16); // col < 65536
            const unsigned long long payload =
                ((unsigned long long)__float_as_uint(v) << 32) | meta;
            bucketed[(size_t)(k * NBUK + b) * BCAP + sub * SCAP + pos] = payload;
        }
    }
}

__global__ void bucket_scan(const int* __restrict__ gcur, int* __restrict__ srtbase)
{
    __shared__ int tot[4 * NBUK];
    for (int i = threadIdx.x; i < 4 * NBUK; i += 256) {
        int t = 0;
#pragma unroll
        for (int s8 = 0; s8 < SUBS; ++s8) t += gcur[i * SUBS + s8];
        tot[i] = t;
    }
    __syncthreads();
    if (threadIdx.x < 4) {
        const int k = threadIdx.x;
        int run = 0;
        for (int b = 0; b < NBUK; ++b) {
            srtbase[k * NBUK + b] = run;
            run += tot[k * NBUK + b];
        }
    }
}

// srt entry: {val_f16 << 16 | col_u16}, row-major, col-half-sorted within row.
__global__ void bucket_sort(const unsigned long long* __restrict__ bucketed,
                            const int* __restrict__ gcur,      // [4][NBUK][SUBS]
                            const int* __restrict__ srtbase,
                            unsigned* __restrict__ srt,
                            int* __restrict__ row_ptr,
                            int* __restrict__ mid)             // [4][N]
{
    const int b = blockIdx.x, k = blockIdx.y, tid = threadIdx.x;
    const int base = srtbase[k * NBUK + b];
    const unsigned long long* bk = bucketed + (size_t)(k * NBUK + b) * BCAP;

    __shared__ int scnt[SUBS];
    __shared__ int rcnt[256][2];
    __shared__ int s[256];
    __shared__ int cur2[256][2];
    rcnt[tid][0] = 0;
    rcnt[tid][1] = 0;
    if (tid < SUBS) scnt[tid] = gcur[(k * NBUK + b) * SUBS + tid];
    __syncthreads();

    for (int s8 = 0; s8 < SUBS; ++s8) {
        const int c8 = scnt[s8];
        for (int i = tid; i < c8; i += 256) {
            const unsigned meta = (unsigned)bk[s8 * SCAP + i];
            atomicAdd(&rcnt[(meta >> 16) & 255][(meta & 0xFFFF) >= COLH], 1);
        }
    }
    __syncthreads();

    const int tot = rcnt[tid][0] + rcnt[tid][1];
    s[tid] = tot;
    __syncthreads();
    for (int off = 1; off < 256; off <<= 1) {
        const int t = (tid >= off) ? s[tid - off] : 0;
        __syncthreads();
        s[tid] += t;
        __syncthreads();
    }
    const int excl = s[tid] - tot;

    const int n = b * 256 + tid;
    if (n < N_NODES) {
        row_ptr[k * NP1 + n] = base + excl;
        mid[k * N_NODES + n] = base + excl + rcnt[tid][0];
    }
    if (b == NBUK - 1 && tid == 0) row_ptr[k * NP1 + N_NODES] = E_ADJ;
    cur2[tid][0] = base + excl;
    cur2[tid][1] = base + excl + rcnt[tid][0];
    __syncthreads();

    for (int s8 = 0; s8 < SUBS; ++s8) {
        const int c8 = scnt[s8];
        for (int i = tid; i < c8; i += 256) {
            const unsigned long long p = bk[s8 * SCAP + i];
            const unsigned meta = (unsigned)p;
            const int rl = (meta >> 16) & 255;
            const int c  = meta & 0xFFFF;
            const float val = __uint_as_float((unsigned)(p >> 32));
            union { f16 h; unsigned short us; } cv;
            cv.h = (f16)val;
            const int pos = atomicAdd(&cur2[rl][c >= COLH], 1);
            srt[(size_t)k * E_ADJ + pos] = ((unsigned)cv.us << 16) | (unsigned)c;
        }
    }
}

// ---------------------------------------------------------------------------
// R24 gather core: octet-4. Lane covers h=(lane&7)*8..+7 (16B f16x8 load);
// es=lane>>3; 4 octs (32 edges) per iteration -> MLP 4. Selectors (p+u)*8+es
// <= 7*8+7 = 63 (no <= 8, p in {0,4}). Zero-pad meta -> pads load row 0
// (L2-hot) scaled by 0. srt meta loads are NT so the stream doesn't evict
// the L2-resident table half. Result valid on lanes 0-7 after 3-round xor.
// ---------------------------------------------------------------------------
__device__ __forceinline__ void gather_oct4(const unsigned* __restrict__ sp,
                                            int s, int en,
                                            const f16* __restrict__ xk,
                                            int lane, float a[8])
{
    const int es = lane >> 3;
    const int hb = (lane & 7) * 8;

    for (int base = s; base < en; base += 64) {
        const int cnt = min(64, en - base);
        unsigned meta = 0;
        if (lane < cnt) meta = ntl_u(&sp[base + lane]);
        const int no = (cnt + 7) >> 3;
        for (int p = 0; p < no; p += 4) {
            unsigned m[4];
#pragma unroll
            for (int u = 0; u < 4; ++u)
                m[u] = __shfl(meta, (p + u) * 8 + es, 64);
            f16x8 g[4];
            float v[4];
#pragma unroll
            for (int u = 0; u < 4; ++u) {
                union { unsigned short us; f16 h; } cv;
                cv.us = (unsigned short)(m[u] >> 16);
                v[u] = (float)cv.h;
                g[u] = *(const f16x8*)(xk + (size_t)(m[u] & 0xFFFF) * HDIM + hb);
            }
#pragma unroll
            for (int u = 0; u < 4; ++u)
#pragma unroll
                for (int j = 0; j < 8; ++j)
                    a[j] = fmaf((float)g[u][j], v[u], a[j]);
        }
    }
#pragma unroll
    for (int j = 0; j < 8; ++j) {
        a[j] += __shfl_xor(a[j], 8, 64);
        a[j] += __shfl_xor(a[j], 16, 64);
        a[j] += __shfl_xor(a[j], 32, 64);
    }
}

// ---------------------------------------------------------------------------
// Half-pass gather. MODE 0: stage-1 spmm (table = t0 + k*N*H).
// MODE 1: agg (table = k&1 ? t1 : t0).  ADD: accumulate onto prior partial.
// RELU applied only on the final pass of stage 1.
// ---------------------------------------------------------------------------
template <int MODE, int ADD, int RELU>
__global__ void gather_half(const unsigned* __restrict__ srt,
                            const int*    __restrict__ row_ptr,
                            const int*    __restrict__ mid,
                            const f16*    __restrict__ t0,
                            const f16*    __restrict__ t1,
                            f16* __restrict__ outb)    // [4][N][H]
{
    const int b = blockIdx.x, k = b & 3, g = b >> 2;        // 50000 blocks
    const int wave = threadIdx.x >> 6, lane = threadIdx.x & 63;
    const int n = g * 4 + wave;

    int s, en;
    if (!ADD) { s = row_ptr[k * NP1 + n]; en = mid[k * N_NODES + n]; }
    else      { s = mid[k * N_NODES + n]; en = row_ptr[k * NP1 + n + 1]; }

    const f16* xk = (MODE == 0) ? (t0 + (size_t)k * N_NODES * HDIM)
                                : ((k & 1) ? t1 : t0);

    float a[8] = {0.f, 0.f, 0.f, 0.f, 0.f, 0.f, 0.f, 0.f};
    gather_oct4(srt + (size_t)k * E_ADJ, s, en, xk, lane, a);

    if (lane < 8) {
        f16* dst = outb + ((size_t)k * N_NODES + n) * HDIM + lane * 8;
        if (ADD) {
            const f16x8 pr = *(const f16x8*)dst;
#pragma unroll
            for (int j = 0; j < 8; ++j) a[j] += (float)pr[j];
        }
        f16x8 o;
#pragma unroll
        for (int j = 0; j < 8; ++j)
            o[j] = RELU ? (f16)fmaxf(a[j], 0.f) : (f16)a[j];
        *(f16x8*)dst = o;
    }
}

// ---------------------------------------------------------------------------
// W fragment pre-pack for mfma_f32_16x16x32_f16 (R15, unchanged).
// ---------------------------------------------------------------------------
__global__ void pack_wfrag(const float* __restrict__ W, const int K,
                           f16* __restrict__ out)
{
    const int idx = blockIdx.x * 256 + threadIdx.x;
    const int j    = idx & 7;
    const int lane = (idx >> 3) & 63;
    const int kcs  = K >> 5;
    int rest = idx >> 9;
    const int kc  = rest % kcs; rest /= kcs;
    const int nt  = rest & 3;
    const int rel = rest >> 2;
    const int k   = kc * 32 + ((lane >> 4) * 8) + j;
    const int col = nt * 16 + (lane & 15);
    out[idx] = (f16)W[((size_t)rel * K + k) * HDIM + col];
}

// ---------------------------------------------------------------------------
// Stage-1 transform via MFMA (R15, unchanged).
// ---------------------------------------------------------------------------
__global__ void gemm1_mfma(const float* __restrict__ x0,
                           const float* __restrict__ x1,
                           const f16* __restrict__ wf,   // [4][4][4][64][8]
                           f16* __restrict__ xw)         // [4][N][64]
{
    const int wave = threadIdx.x >> 6;   // relation
    const int lane = threadIdx.x & 63;
    const int n0 = blockIdx.x * 32;      // 1563 blocks cover 50016 (guarded)
    const int q = lane >> 4, r16 = lane & 15;

    const float* xr = (wave & 1) ? x1 : x0;

    f16x8 b[4][4];
#pragma unroll
    for (int nt = 0; nt < 4; ++nt)
#pragma unroll
        for (int kc = 0; kc < 4; ++kc)
            b[nt][kc] = *(const f16x8*)(wf + (((size_t)(wave * 4 + nt) * 4 + kc) * 64 + lane) * 8);

    for (int t = 0; t < 2; ++t) {
        const int row = n0 + t * 16 + r16;
        const int rowc = row < N_NODES ? row : N_NODES - 1;
        f16x8 a[4];
#pragma unroll
        for (int kc = 0; kc < 4; ++kc) {
            const float4 lo = *(const float4*)(xr + (size_t)rowc * FDIM + kc * 32 + q * 8);
            const float4 hi = *(const float4*)(xr + (size_t)rowc * FDIM + kc * 32 + q * 8 + 4);
            f16x8 av;
            av[0] = (f16)lo.x; av[1] = (f16)lo.y; av[2] = (f16)lo.z; av[3] = (f16)lo.w;
            av[4] = (f16)hi.x; av[5] = (f16)hi.y; av[6] = (f16)hi.z; av[7] = (f16)hi.w;
            a[kc] = av;
        }
#pragma unroll
        for (int nt = 0; nt < 4; ++nt) {
            f32x4 acc = {0.f, 0.f, 0.f, 0.f};
#pragma unroll
            for (int kc = 0; kc < 4; ++kc)
                acc = __builtin_amdgcn_mfma_f32_16x16x32_f16(a[kc], b[nt][kc], acc, 0, 0, 0);
#pragma unroll
            for (int j = 0; j < 4; ++j) {
                const int n = n0 + t * 16 + q * 4 + j;
                if (n < N_NODES)
                    xw[((size_t)wave * N_NODES + n) * HDIM + nt * 16 + r16] = (f16)acc[j];
            }
        }
    }
}

// ---------------------------------------------------------------------------
// Stages 2-4 transform via MFMA + fused relu + pairwise combine (R15).
// ---------------------------------------------------------------------------
__global__ void gemm2_mfma(const f16* __restrict__ agg,  // [4][N][64]
                           const f16* __restrict__ wf,   // [4][4][2][64][8]
                           f16* __restrict__ h0, f16* __restrict__ h1)
{
    const int wave = threadIdx.x >> 6;
    const int lane = threadIdx.x & 63;
    const int tid  = threadIdx.x;
    const int n0 = blockIdx.x * 32;
    const int q = lane >> 4, r16 = lane & 15;

    f16x8 b[4][2];
#pragma unroll
    for (int nt = 0; nt < 4; ++nt)
#pragma unroll
        for (int kc = 0; kc < 2; ++kc)
            b[nt][kc] = *(const f16x8*)(wf + (((size_t)(wave * 4 + nt) * 2 + kc) * 64 + lane) * 8);

    __shared__ f16 yt[4][16][HDIM];

    for (int t = 0; t < 2; ++t) {
        const int row = n0 + t * 16 + r16;
        const int rowc = row < N_NODES ? row : N_NODES - 1;
        f16x8 a[2];
#pragma unroll
        for (int kc = 0; kc < 2; ++kc)
            a[kc] = *(const f16x8*)(agg + ((size_t)wave * N_NODES + rowc) * HDIM + kc * 32 + q * 8);

#pragma unroll
        for (int nt = 0; nt < 4; ++nt) {
            f32x4 acc = {0.f, 0.f, 0.f, 0.f};
#pragma unroll
            for (int kc = 0; kc < 2; ++kc)
                acc = __builtin_amdgcn_mfma_f32_16x16x32_f16(a[kc], b[nt][kc], acc, 0, 0, 0);
#pragma unroll
            for (int j = 0; j < 4; ++j)
                yt[wave][q * 4 + j][nt * 16 + r16] = (f16)fmaxf(acc[j], 0.f);
        }
        __syncthreads();

        {
            const int r  = tid >> 4;          // 0..15
            const int c4 = (tid & 15) * 4;    // 0..60
            const int n  = n0 + t * 16 + r;
            if (n < N_NODES) {
                const f16x4 a0 = *(const f16x4*)&yt[0][r][c4];
                const f16x4 a1 = *(const f16x4*)&yt[1][r][c4];
                const f16x4 a2 = *(const f16x4*)&yt[2][r][c4];
                const f16x4 a3 = *(const f16x4*)&yt[3][r][c4];
                f16x4 o0, o1;
#pragma unroll
                for (int u = 0; u < 4; ++u) {
                    o0[u] = (f16)((float)a0[u] + (float)a1[u]);
                    o1[u] = (f16)((float)a2[u] + (float)a3[u]);
                }
                *(f16x4*)(h0 + (size_t)n * HDIM + c4) = o0;
                *(f16x4*)(h1 + (size_t)n * HDIM + c4) = o1;
            }
        }
        __syncthreads();
    }
}

// h0 = y0+y1, h1 = y2+y3 (y already relu'd per relation).
__global__ void combine_kernel(const f16* __restrict__ y,
                               f16* __restrict__ h0, f16* __restrict__ h1)
{
    const size_t NHh = (size_t)N_NODES * HDIM / 2;
    const size_t i = (size_t)blockIdx.x * 256 + threadIdx.x;   // 6250 blocks exact
    const f16x2 a = ((const f16x2*)y)[i];
    const f16x2 b = ((const f16x2*)y)[NHh + i];
    const f16x2 c = ((const f16x2*)y)[2 * NHh + i];
    const f16x2 d = ((const f16x2*)y)[3 * NHh + i];
    f16x2 o0, o1;
    o0.x = (f16)((float)a.x + (float)b.x);
    o0.y = (f16)((float)a.y + (float)b.y);
    o1.x = (f16)((float)c.x + (float)d.x);
    o1.y = (f16)((float)c.y + (float)d.y);
    ((f16x2*)h0)[i] = o0;
    ((f16x2*)h1)[i] = o1;
}

// ---------------------------------------------------------------------------
__global__ void make_M(const float* __restrict__ R, const float* __restrict__ Dl,
                       const int* __restrict__ rt_k, float* __restrict__ M)
{
    const int i = blockIdx.x * blockDim.x + threadIdx.x;
    if (i >= HDIM * HDIM) return;
    const float* d = Dl + rt_k[0] * HDIM;
    M[i] = d[i >> 6] * R[i] * d[i & 63];
}

// A[n][g] = sum_h h0[n][h] * M[h][g]   (fp16 out)
__global__ void h0M_kernel(const f16* __restrict__ h0, const float* __restrict__ M,
                           f16* __restrict__ A)
{
    const int wave = threadIdx.x >> 6, lane = threadIdx.x & 63;
    const int n0 = blockIdx.x * 16;      // 3125 blocks

    __shared__ float sx[16][HDIM];
    for (int i = threadIdx.x; i < 16 * HDIM; i += 256)
        sx[i >> 6][i & 63] = (float)h0[(size_t)n0 * HDIM + i];
    __syncthreads();

    float acc[4] = {0.f, 0.f, 0.f, 0.f};
#pragma unroll 4
    for (int f = 0; f < HDIM; ++f) {
        const float w = M[f * HDIM + lane];
#pragma unroll
        for (int r = 0; r < 4; ++r)
            acc[r] = fmaf(sx[wave * 4 + r][f], w, acc[r]);
    }
#pragma unroll
    for (int r = 0; r < 4; ++r)
        A[(size_t)(n0 + wave * 4 + r) * HDIM + lane] = (f16)acc[r];
}

// preds[e] = dot(A[i], h1[j]) — 4 edges/wave, f16x4 (8B) loads (R16).
__global__ void decode(const f16* __restrict__ A, const f16* __restrict__ h1,
                       const int* __restrict__ edges, float* __restrict__ out)
{
    const int w = (blockIdx.x * 256 + threadIdx.x) >> 6;   // 12500 blocks -> 50000 waves
    const int lane = threadIdx.x & 63;
    const int e = w * 4 + (lane >> 4);                     // 4 edges per wave
    const int q = lane & 15;

    const int i = edges[2 * (size_t)e];
    const int j = edges[2 * (size_t)e + 1];

    const f16x4 a = *(const f16x4*)(A + (size_t)i * HDIM + q * 4);
    const f16x4 b = *(const f16x4*)(h1 + (size_t)j * HDIM + q * 4);
    float p = 0.f;
#pragma unroll
    for (int u = 0; u < 4; ++u)
        p = fmaf((float)a[u], (float)b[u], p);
    p += __shfl_xor(p, 1, 64);
    p += __shfl_xor(p, 2, 64);
    p += __shfl_xor(p, 4, 64);
    p += __shfl_xor(p, 8, 64);
    if (q == 0) out[e] = p;
}

// ---------------------------------------------------------------------------
static void build_csr(const int* rows, const int* cols, const float* vals,
                      int* gcur, int* srtbase, unsigned long long* bucketed,
                      unsigned* srt, int* row_ptr, int* mid, hipStream_t stream)
{
    hipMemsetAsync(gcur, 0, 4 * NBUK * SUBS * sizeof(int), stream);
    part_kernel<<<dim3(NPBLK, 4), 256, 0, stream>>>(rows, cols, vals, gcur, bucketed);
    bucket_scan<<<1, 256, 0, stream>>>(gcur, srtbase);
    bucket_sort<<<dim3(NBUK, 4), 256, 0, stream>>>(bucketed, gcur, srtbase, srt, row_ptr, mid);
}

extern "C" void kernel_launch(void* const* d_in, const int* in_sizes, int n_in,
                              void* d_out, int out_size, void* d_ws, size_t ws_size,
                              hipStream_t stream) {
    const int*   adj_rows = (const int*)  d_in[0];
    const int*   adj_cols = (const int*)  d_in[1];
    const float* adj_vals = (const float*)d_in[2];
    const float* feat0    = (const float*)d_in[3];
    const float* feat1    = (const float*)d_in[4];
    const float* W1       = (const float*)d_in[5];
    const float* W2       = (const float*)d_in[6];
    const float* W3       = (const float*)d_in[7];
    const float* W4       = (const float*)d_in[8];
    const float* Rg       = (const float*)d_in[9];
    const float* Dl       = (const float*)d_in[10];
    const int*   edges    = (const int*)  d_in[11];
    const int*   rt_k     = (const int*)  d_in[12];
    float* out = (float*)d_out;

    const size_t NH = (size_t)N_NODES * HDIM;       // 3.2M
    float* ws = (float*)d_ws;
    // layout (float offsets):
    f16*      xwh     = (f16*)ws;                     // 4*NH halfs (table / agg / A)
    f16*      h0      = (f16*)(ws + 2 * NH);          // NH halfs
    f16*      h1      = (f16*)(ws + 2 * NH + NH / 2); // NH halfs
    unsigned* srt     = (unsigned*)(ws + 3 * NH);     // 4E u32 (12.8MB)
    int*      row_ptr = (int*)(ws + 3 * NH + 8 * (size_t)E_ADJ); // 4*(N+1)
    int*      gcur    = row_ptr + 4 * NP1 + 60;       // 4*NBUK*SUBS
    int*      srtbase = gcur + 4 * NBUK * SUBS;       // 4*NBUK
    int*      mid     = srtbase + 4 * NBUK + 32;      // 4*N
    float*    M       = (float*)(mid + 4 * N_NODES + 32);        // 4096 f
    unsigned long long* bucketed =
        (unsigned long long*)(M + HDIM * HDIM + 64);             // 4*NBUK*BCAP u64 = 38.5MB
    // y aliases bucketed: y live only in stage 1 (after build A, before build B).
    f16* y = (f16*)bucketed;                          // 4*NH halfs = 25.6MB < 38.5MB
    // W fragment tables after bucketed: 81920 f16 = 160KB
    f16* wfrag = (f16*)(bucketed + (size_t)4 * NBUK * BCAP);
    f16* wf1 = wfrag;            // 32768 f16
    f16* wf2 = wfrag + 32768;    // 16384 f16
    f16* wf3 = wfrag + 49152;    // 16384 f16
    f16* wf4 = wfrag + 65536;    // 16384 f16
    // total ~= 26M floats ~= 105 MB (<= R1's proven 128 MB)

    const int* r2 = adj_rows + 4 * (size_t)E_ADJ;
    const int* c2 = adj_cols + 4 * (size_t)E_ADJ;
    const float* v2 = adj_vals + 4 * (size_t)E_ADJ;

    // ---- pre-pack W fragments ----
    pack_wfrag<<<128, 256, 0, stream>>>(W1, FDIM, wf1);
    pack_wfrag<<<64, 256, 0, stream>>>(W2, HDIM, wf2);
    pack_wfrag<<<64, 256, 0, stream>>>(W3, HDIM, wf3);
    pack_wfrag<<<64, 256, 0, stream>>>(W4, HDIM, wf4);

    // ---- CSR for adjacency group A (stages 1 & 2) ----
    build_csr(adj_rows, adj_cols, adj_vals, gcur, srtbase, bucketed, srt, row_ptr, mid, stream);

    // ---- stage 1: transform (MFMA) then aggregate (2 col-half passes) ----
    gemm1_mfma<<<1563, 256, 0, stream>>>(feat0, feat1, wf1, xwh);
    gather_half<0, 0, 0><<<N_NODES, 256, 0, stream>>>(srt, row_ptr, mid, xwh, xwh, y);
    gather_half<0, 1, 1><<<N_NODES, 256, 0, stream>>>(srt, row_ptr, mid, xwh, xwh, y);
    combine_kernel<<<(int)(NH / 2 / 256), 256, 0, stream>>>(y, h0, h1);

    // ---- stage 2: aggregate (2 passes) then transform (MFMA) ----
    gather_half<1, 0, 0><<<N_NODES, 256, 0, stream>>>(srt, row_ptr, mid, h0, h1, xwh);
    gather_half<1, 1, 0><<<N_NODES, 256, 0, stream>>>(srt, row_ptr, mid, h0, h1, xwh);
    gemm2_mfma<<<1563, 256, 0, stream>>>(xwh, wf2, h0, h1);

    // ---- CSR for adjacency group B (stages 3 & 4) ----
    build_csr(r2, c2, v2, gcur, srtbase, bucketed, srt, row_ptr, mid, stream);

    // ---- stage 3 ----
    gather_half<1, 0, 0><<<N_NODES, 256, 0, stream>>>(srt, row_ptr, mid, h0, h1, xwh);
    gather_half<1, 1, 0><<<N_NODES, 256, 0, stream>>>(srt, row_ptr, mid, h0, h1, xwh);
    gemm2_mfma<<<1563, 256, 0, stream>>>(xwh, wf3, h0, h1);

    // ---- stage 4 ----
    gather_half<1, 0, 0><<<N_NODES, 256, 0, stream>>>(srt, row_ptr, mid, h0, h1, xwh);
    gather_half<1, 1, 0><<<N_NODES, 256, 0, stream>>>(srt, row_ptr, mid, h0, h1, xwh);
    gemm2_mfma<<<1563, 256, 0, stream>>>(xwh, wf4, h0, h1);

    // ---- decode: M, A = h0@M (fp16, aliases xwh), dot per edge ----
    make_M<<<(HDIM * HDIM + 255) / 256, 256, 0, stream>>>(Rg, Dl, rt_k, M);
    f16* A = xwh;
    h0M_kernel<<<N_NODES / 16, 256, 0, stream>>>(h0, M, A);
    decode<<<E_DEC * 16 / 256, 256, 0, stream>>>(A, h1, edges, out);
}

// Round 25
// 549.041 us; speedup vs baseline: 1.5956x; 1.5956x over previous
//
#include <hip/hip_runtime.h>

#define N_NODES 50000
#define E_ADJ   800000
#define E_DEC   200000
#define FDIM    128
#define HDIM    64
#define NP1     (N_NODES + 1)
#define NBUK    196            // ceil(50000/256) buckets of 256 rows
#define SUBS    32             // sub-counters per bucket (blockIdx & 31)
#define SCAP    192            // per-sub capacity (mean 127.5, +5.7 sigma)
#define BCAP    (SUBS * SCAP)  // 6144 per bucket
#define TILE_E  1024           // edges per part-block (R20 TLP win)
#define EPB     4              // edges per thread
#define NPBLK   782            // ceil(E_ADJ/TILE_E)

typedef _Float16 f16;
typedef __attribute__((ext_vector_type(2))) _Float16 f16x2;
typedef __attribute__((ext_vector_type(4))) _Float16 f16x4;
typedef __attribute__((ext_vector_type(8))) _Float16 f16x8;
typedef __attribute__((ext_vector_type(4))) float f32x4;

__device__ __forceinline__ int   ntl_i(const int* p)   { return __builtin_nontemporal_load(p); }
__device__ __forceinline__ float ntl_f(const float* p) { return __builtin_nontemporal_load(p); }

// ---------------------------------------------------------------------------
// CSR build. part_kernel = R20 (TILE_E 1024, 4x TLP, no per-thread arrays);
// bucket_sort = R19 direct-global form. R24 lesson: gathers are VALU-issue
// bound (FETCH halved, dur rose) — no more byte-targeting on them.
// ---------------------------------------------------------------------------
__global__ void part_kernel(const int* __restrict__ rows,
                            const int* __restrict__ cols,
                            const float* __restrict__ vals,
                            int* __restrict__ gcur,            // [4][NBUK][SUBS]
                            unsigned long long* __restrict__ bucketed)
{
    const int k   = blockIdx.y;
    const int sub = blockIdx.x & (SUBS - 1);
    const int tid = threadIdx.x;
    const long long t0 = (long long)blockIdx.x * TILE_E;

    __shared__ int hist[NBUK];
    __shared__ int cur[NBUK];
    for (int i = tid; i < NBUK; i += 256) hist[i] = 0;
    __syncthreads();

    for (int it = 0; it < EPB; ++it) {
        const long long e = t0 + it * 256 + tid;
        if (e < E_ADJ) {
            const int r = rows[(size_t)k * E_ADJ + e];
            atomicAdd(&hist[r >> 8], 1);
        }
    }
    __syncthreads();

    for (int i = tid; i < NBUK; i += 256)
        cur[i] = (hist[i] > 0) ? atomicAdd(&gcur[(k * NBUK + i) * SUBS + sub], hist[i]) : 0;
    __syncthreads();

    for (int it = 0; it < EPB; ++it) {
        const long long e = t0 + it * 256 + tid;
        if (e < E_ADJ) {
            const int r = rows[(size_t)k * E_ADJ + e];
            const int b = r >> 8;
            const int pos = atomicAdd(&cur[b], 1);
            const int c = ntl_i(&cols[(size_t)k * E_ADJ + e]);
            const float v = ntl_f(&vals[(size_t)k * E_ADJ + e]);
            const unsigned meta = (unsigned)c | ((unsigned)(r & 255) << 16); // col < 65536
            const unsigned long long payload =
                ((unsigned long long)__float_as_uint(v) << 32) | meta;
            bucketed[(size_t)(k * NBUK + b) * BCAP + sub * SCAP + pos] = payload;
        }
    }
}

__global__ void bucket_scan(const int* __restrict__ gcur, int* __restrict__ srtbase)
{
    __shared__ int tot[4 * NBUK];
    for (int i = threadIdx.x; i < 4 * NBUK; i += 256) {
        int t = 0;
#pragma unroll
        for (int s8 = 0; s8 < SUBS; ++s8) t += gcur[i * SUBS + s8];
        tot[i] = t;
    }
    __syncthreads();
    if (threadIdx.x < 4) {
        const int k = threadIdx.x;
        int run = 0;
        for (int b = 0; b < NBUK; ++b) {
            srtbase[k * NBUK + b] = run;
            run += tot[k * NBUK + b];
        }
    }
}

// srt entry: {val_f16 << 16 | col_u16}. Direct global reads (R19 form).
__global__ void bucket_sort(const unsigned long long* __restrict__ bucketed,
                            const int* __restrict__ gcur,      // [4][NBUK][SUBS]
                            const int* __restrict__ srtbase,
                            unsigned* __restrict__ srt,
                            int* __restrict__ row_ptr)
{
    const int b = blockIdx.x, k = blockIdx.y, tid = threadIdx.x;
    const int base = srtbase[k * NBUK + b];
    const unsigned long long* bk = bucketed + (size_t)(k * NBUK + b) * BCAP;

    __shared__ int scnt[SUBS];
    __shared__ int s[256];
    __shared__ int cur[256];
    __shared__ int rcnt[256];
    rcnt[tid] = 0;
    if (tid < SUBS) scnt[tid] = gcur[(k * NBUK + b) * SUBS + tid];
    __syncthreads();

    for (int s8 = 0; s8 < SUBS; ++s8) {
        const int c8 = scnt[s8];
        for (int i = tid; i < c8; i += 256) {
            const unsigned meta = (unsigned)bk[s8 * SCAP + i];
            atomicAdd(&rcnt[(meta >> 16) & 255], 1);
        }
    }
    __syncthreads();

    const int v = rcnt[tid];
    s[tid] = v;
    __syncthreads();
    for (int off = 1; off < 256; off <<= 1) {
        const int t = (tid >= off) ? s[tid - off] : 0;
        __syncthreads();
        s[tid] += t;
        __syncthreads();
    }
    const int excl = s[tid] - v;

    const int n = b * 256 + tid;
    if (n < N_NODES) row_ptr[k * NP1 + n] = base + excl;
    if (b == NBUK - 1 && tid == 0) row_ptr[k * NP1 + N_NODES] = E_ADJ;
    cur[tid] = base + excl;
    __syncthreads();

    for (int s8 = 0; s8 < SUBS; ++s8) {
        const int c8 = scnt[s8];
        for (int i = tid; i < c8; i += 256) {
            const unsigned long long p = bk[s8 * SCAP + i];
            const unsigned meta = (unsigned)p;
            const int rl = (meta >> 16) & 255;
            const int c  = meta & 0xFFFF;
            const float val = __uint_as_float((unsigned)(p >> 32));
            union { f16 h; unsigned short us; } cv;
            cv.h = (f16)val;
            const int pos = atomicAdd(&cur[rl], 1);
            srt[(size_t)k * E_ADJ + pos] = ((unsigned)cv.us << 16) | (unsigned)c;
        }
    }
}

// ---------------------------------------------------------------------------
// R16 quad gather (best measured: 67us/dispatch @ VALUBusy 58%).
// Lane covers h=(lane&15)*4..+3 (8B f16x4 load); es=lane>>4 -> 4 edges in
// flight. Result valid on lanes 0-15 after 2-round xor reduce.
// ---------------------------------------------------------------------------
__device__ __forceinline__ void gather_quads(const unsigned* __restrict__ sp,
                                             int s, int en,
                                             const f16* __restrict__ xk,
                                             int lane, float a[4])
{
    const int es = lane >> 4;
    const int hb = (lane & 15) * 4;

    for (int base = s; base < en; base += 64) {
        const int cnt = min(64, en - base);
        unsigned meta = 0;
        if (lane < cnt) meta = sp[base + lane];
        const int nq = (cnt + 3) >> 2;
        int p = 0;
        for (; p + 4 <= nq; p += 4) {
            unsigned m[4];
#pragma unroll
            for (int u = 0; u < 4; ++u)
                m[u] = __shfl(meta, (p + u) * 4 + es, 64);
            f16x4 g[4];
            float v[4];
#pragma unroll
            for (int u = 0; u < 4; ++u) {
                union { unsigned short us; f16 h; } cv;
                cv.us = (unsigned short)(m[u] >> 16);
                v[u] = (float)cv.h;
                g[u] = *(const f16x4*)(xk + (size_t)(m[u] & 0xFFFF) * HDIM + hb);
            }
#pragma unroll
            for (int u = 0; u < 4; ++u) {
                a[0] = fmaf((float)g[u][0], v[u], a[0]);
                a[1] = fmaf((float)g[u][1], v[u], a[1]);
                a[2] = fmaf((float)g[u][2], v[u], a[2]);
                a[3] = fmaf((float)g[u][3], v[u], a[3]);
            }
        }
        for (; p < nq; ++p) {
            const unsigned m = __shfl(meta, p * 4 + es, 64);
            union { unsigned short us; f16 h; } cv;
            cv.us = (unsigned short)(m >> 16);
            const float v = (float)cv.h;
            const f16x4 g = *(const f16x4*)(xk + (size_t)(m & 0xFFFF) * HDIM + hb);
            a[0] = fmaf((float)g[0], v, a[0]);
            a[1] = fmaf((float)g[1], v, a[1]);
            a[2] = fmaf((float)g[2], v, a[2]);
            a[3] = fmaf((float)g[3], v, a[3]);
        }
    }
#pragma unroll
    for (int j = 0; j < 4; ++j) {
        a[j] += __shfl_xor(a[j], 16, 64);
        a[j] += __shfl_xor(a[j], 32, 64);
    }
}

// ---------------------------------------------------------------------------
// W fragment pre-pack for mfma_f32_16x16x32_f16 (R15, unchanged).
// ---------------------------------------------------------------------------
__global__ void pack_wfrag(const float* __restrict__ W, const int K,
                           f16* __restrict__ out)
{
    const int idx = blockIdx.x * 256 + threadIdx.x;
    const int j    = idx & 7;
    const int lane = (idx >> 3) & 63;
    const int kcs  = K >> 5;
    int rest = idx >> 9;
    const int kc  = rest % kcs; rest /= kcs;
    const int nt  = rest & 3;
    const int rel = rest >> 2;
    const int k   = kc * 32 + ((lane >> 4) * 8) + j;
    const int col = nt * 16 + (lane & 15);
    out[idx] = (f16)W[((size_t)rel * K + k) * HDIM + col];
}

// ---------------------------------------------------------------------------
// Stage-1 transform via MFMA (R15, unchanged).
// ---------------------------------------------------------------------------
__global__ void gemm1_mfma(const float* __restrict__ x0,
                           const float* __restrict__ x1,
                           const f16* __restrict__ wf,   // [4][4][4][64][8]
                           f16* __restrict__ xw)         // [4][N][64]
{
    const int wave = threadIdx.x >> 6;   // relation
    const int lane = threadIdx.x & 63;
    const int n0 = blockIdx.x * 32;      // 1563 blocks cover 50016 (guarded)
    const int q = lane >> 4, r16 = lane & 15;

    const float* xr = (wave & 1) ? x1 : x0;

    f16x8 b[4][4];
#pragma unroll
    for (int nt = 0; nt < 4; ++nt)
#pragma unroll
        for (int kc = 0; kc < 4; ++kc)
            b[nt][kc] = *(const f16x8*)(wf + (((size_t)(wave * 4 + nt) * 4 + kc) * 64 + lane) * 8);

    for (int t = 0; t < 2; ++t) {
        const int row = n0 + t * 16 + r16;
        const int rowc = row < N_NODES ? row : N_NODES - 1;
        f16x8 a[4];
#pragma unroll
        for (int kc = 0; kc < 4; ++kc) {
            const float4 lo = *(const float4*)(xr + (size_t)rowc * FDIM + kc * 32 + q * 8);
            const float4 hi = *(const float4*)(xr + (size_t)rowc * FDIM + kc * 32 + q * 8 + 4);
            f16x8 av;
            av[0] = (f16)lo.x; av[1] = (f16)lo.y; av[2] = (f16)lo.z; av[3] = (f16)lo.w;
            av[4] = (f16)hi.x; av[5] = (f16)hi.y; av[6] = (f16)hi.z; av[7] = (f16)hi.w;
            a[kc] = av;
        }
#pragma unroll
        for (int nt = 0; nt < 4; ++nt) {
            f32x4 acc = {0.f, 0.f, 0.f, 0.f};
#pragma unroll
            for (int kc = 0; kc < 4; ++kc)
                acc = __builtin_amdgcn_mfma_f32_16x16x32_f16(a[kc], b[nt][kc], acc, 0, 0, 0);
#pragma unroll
            for (int j = 0; j < 4; ++j) {
                const int n = n0 + t * 16 + q * 4 + j;
                if (n < N_NODES)
                    xw[((size_t)wave * N_NODES + n) * HDIM + nt * 16 + r16] = (f16)acc[j];
            }
        }
    }
}

// ---------------------------------------------------------------------------
// Stages 2-4 transform via MFMA + fused relu + pairwise combine (R15).
// ---------------------------------------------------------------------------
__global__ void gemm2_mfma(const f16* __restrict__ agg,  // [4][N][64]
                           const f16* __restrict__ wf,   // [4][4][2][64][8]
                           f16* __restrict__ h0, f16* __restrict__ h1)
{
    const int wave = threadIdx.x >> 6;
    const int lane = threadIdx.x & 63;
    const int tid  = threadIdx.x;
    const int n0 = blockIdx.x * 32;
    const int q = lane >> 4, r16 = lane & 15;

    f16x8 b[4][2];
#pragma unroll
    for (int nt = 0; nt < 4; ++nt)
#pragma unroll
        for (int kc = 0; kc < 2; ++kc)
            b[nt][kc] = *(const f16x8*)(wf + (((size_t)(wave * 4 + nt) * 2 + kc) * 64 + lane) * 8);

    __shared__ f16 yt[4][16][HDIM];

    for (int t = 0; t < 2; ++t) {
        const int row = n0 + t * 16 + r16;
        const int rowc = row < N_NODES ? row : N_NODES - 1;
        f16x8 a[2];
#pragma unroll
        for (int kc = 0; kc < 2; ++kc)
            a[kc] = *(const f16x8*)(agg + ((size_t)wave * N_NODES + rowc) * HDIM + kc * 32 + q * 8);

#pragma unroll
        for (int nt = 0; nt < 4; ++nt) {
            f32x4 acc = {0.f, 0.f, 0.f, 0.f};
#pragma unroll
            for (int kc = 0; kc < 2; ++kc)
                acc = __builtin_amdgcn_mfma_f32_16x16x32_f16(a[kc], b[nt][kc], acc, 0, 0, 0);
#pragma unroll
            for (int j = 0; j < 4; ++j)
                yt[wave][q * 4 + j][nt * 16 + r16] = (f16)fmaxf(acc[j], 0.f);
        }
        __syncthreads();

        {
            const int r  = tid >> 4;          // 0..15
            const int c4 = (tid & 15) * 4;    // 0..60
            const int n  = n0 + t * 16 + r;
            if (n < N_NODES) {
                const f16x4 a0 = *(const f16x4*)&yt[0][r][c4];
                const f16x4 a1 = *(const f16x4*)&yt[1][r][c4];
                const f16x4 a2 = *(const f16x4*)&yt[2][r][c4];
                const f16x4 a3 = *(const f16x4*)&yt[3][r][c4];
                f16x4 o0, o1;
#pragma unroll
                for (int u = 0; u < 4; ++u) {
                    o0[u] = (f16)((float)a0[u] + (float)a1[u]);
                    o1[u] = (f16)((float)a2[u] + (float)a3[u]);
                }
                *(f16x4*)(h0 + (size_t)n * HDIM + c4) = o0;
                *(f16x4*)(h1 + (size_t)n * HDIM + c4) = o1;
            }
        }
        __syncthreads();
    }
}

// ---------------------------------------------------------------------------
// Stage-1 SPMM, relation-per-block + quad gathers (R16 form).
// ---------------------------------------------------------------------------
__global__ void spmm_csr(const unsigned* __restrict__ srt,
                         const int*    __restrict__ row_ptr,
                         const f16*    __restrict__ xw,     // [4][N][H]
                         f16* __restrict__ y)               // [4][N][H] relu'd
{
    const int b = blockIdx.x, k = b & 3, g = b >> 2;        // 50000 blocks
    const int wave = threadIdx.x >> 6, lane = threadIdx.x & 63;
    const int n = g * 4 + wave;

    const int s  = row_ptr[k * NP1 + n];
    const int en = row_ptr[k * NP1 + n + 1];
    float a[4] = {0.f, 0.f, 0.f, 0.f};
    gather_quads(srt + (size_t)k * E_ADJ, s, en,
                 xw + (size_t)k * N_NODES * HDIM, lane, a);
    if (lane < 16) {
        f16x4 o;
        o[0] = (f16)fmaxf(a[0], 0.f);
        o[1] = (f16)fmaxf(a[1], 0.f);
        o[2] = (f16)fmaxf(a[2], 0.f);
        o[3] = (f16)fmaxf(a[3], 0.f);
        *(f16x4*)(y + ((size_t)k * N_NODES + n) * HDIM + lane * 4) = o;
    }
}

// h0 = y0+y1, h1 = y2+y3 (y already relu'd per relation).
__global__ void combine_kernel(const f16* __restrict__ y,
                               f16* __restrict__ h0, f16* __restrict__ h1)
{
    const size_t NHh = (size_t)N_NODES * HDIM / 2;
    const size_t i = (size_t)blockIdx.x * 256 + threadIdx.x;   // 6250 blocks exact
    const f16x2 a = ((const f16x2*)y)[i];
    const f16x2 b = ((const f16x2*)y)[NHh + i];
    const f16x2 c = ((const f16x2*)y)[2 * NHh + i];
    const f16x2 d = ((const f16x2*)y)[3 * NHh + i];
    f16x2 o0, o1;
    o0.x = (f16)((float)a.x + (float)b.x);
    o0.y = (f16)((float)a.y + (float)b.y);
    o1.x = (f16)((float)c.x + (float)d.x);
    o1.y = (f16)((float)c.y + (float)d.y);
    ((f16x2*)h0)[i] = o0;
    ((f16x2*)h1)[i] = o1;
}

// ---------------------------------------------------------------------------
// Stages 2-4 aggregate, relation-per-block + quad gathers (R16 form).
// ---------------------------------------------------------------------------
__global__ void agg_csr(const unsigned* __restrict__ srt,
                        const int*    __restrict__ row_ptr,
                        const f16*    __restrict__ h0,
                        const f16*    __restrict__ h1,
                        f16* __restrict__ agg)    // [4][N][H]
{
    const int b = blockIdx.x, k = b & 3, g = b >> 2;        // 50000 blocks
    const int wave = threadIdx.x >> 6, lane = threadIdx.x & 63;
    const int n = g * 4 + wave;

    const int s  = row_ptr[k * NP1 + n];
    const int en = row_ptr[k * NP1 + n + 1];
    const f16* xk = (k & 1) ? h1 : h0;
    float a[4] = {0.f, 0.f, 0.f, 0.f};
    gather_quads(srt + (size_t)k * E_ADJ, s, en, xk, lane, a);
    if (lane < 16) {
        f16x4 o;
        o[0] = (f16)a[0];
        o[1] = (f16)a[1];
        o[2] = (f16)a[2];
        o[3] = (f16)a[3];
        *(f16x4*)(agg + ((size_t)k * N_NODES + n) * HDIM + lane * 4) = o;
    }
}

// ---------------------------------------------------------------------------
__global__ void make_M(const float* __restrict__ R, const float* __restrict__ Dl,
                       const int* __restrict__ rt_k, float* __restrict__ M)
{
    const int i = blockIdx.x * blockDim.x + threadIdx.x;
    if (i >= HDIM * HDIM) return;
    const float* d = Dl + rt_k[0] * HDIM;
    M[i] = d[i >> 6] * R[i] * d[i & 63];
}

// A[n][g] = sum_h h0[n][h] * M[h][g]   (fp16 out)
__global__ void h0M_kernel(const f16* __restrict__ h0, const float* __restrict__ M,
                           f16* __restrict__ A)
{
    const int wave = threadIdx.x >> 6, lane = threadIdx.x & 63;
    const int n0 = blockIdx.x * 16;      // 3125 blocks

    __shared__ float sx[16][HDIM];
    for (int i = threadIdx.x; i < 16 * HDIM; i += 256)
        sx[i >> 6][i & 63] = (float)h0[(size_t)n0 * HDIM + i];
    __syncthreads();

    float acc[4] = {0.f, 0.f, 0.f, 0.f};
#pragma unroll 4
    for (int f = 0; f < HDIM; ++f) {
        const float w = M[f * HDIM + lane];
#pragma unroll
        for (int r = 0; r < 4; ++r)
            acc[r] = fmaf(sx[wave * 4 + r][f], w, acc[r]);
    }
#pragma unroll
    for (int r = 0; r < 4; ++r)
        A[(size_t)(n0 + wave * 4 + r) * HDIM + lane] = (f16)acc[r];
}

// preds[e] = dot(A[i], h1[j]) — 4 edges/wave, f16x4 (8B) loads (R16).
__global__ void decode(const f16* __restrict__ A, const f16* __restrict__ h1,
                       const int* __restrict__ edges, float* __restrict__ out)
{
    const int w = (blockIdx.x * 256 + threadIdx.x) >> 6;   // 12500 blocks -> 50000 waves
    const int lane = threadIdx.x & 63;
    const int e = w * 4 + (lane >> 4);                     // 4 edges per wave
    const int q = lane & 15;

    const int i = edges[2 * (size_t)e];
    const int j = edges[2 * (size_t)e + 1];

    const f16x4 a = *(const f16x4*)(A + (size_t)i * HDIM + q * 4);
    const f16x4 b = *(const f16x4*)(h1 + (size_t)j * HDIM + q * 4);
    float p = 0.f;
#pragma unroll
    for (int u = 0; u < 4; ++u)
        p = fmaf((float)a[u], (float)b[u], p);
    p += __shfl_xor(p, 1, 64);
    p += __shfl_xor(p, 2, 64);
    p += __shfl_xor(p, 4, 64);
    p += __shfl_xor(p, 8, 64);
    if (q == 0) out[e] = p;
}

// ---------------------------------------------------------------------------
static void build_csr(const int* rows, const int* cols, const float* vals,
                      int* gcur, int* srtbase, unsigned long long* bucketed,
                      unsigned* srt, int* row_ptr, hipStream_t stream)
{
    hipMemsetAsync(gcur, 0, 4 * NBUK * SUBS * sizeof(int), stream);
    part_kernel<<<dim3(NPBLK, 4), 256, 0, stream>>>(rows, cols, vals, gcur, bucketed);
    bucket_scan<<<1, 256, 0, stream>>>(gcur, srtbase);
    bucket_sort<<<dim3(NBUK, 4), 256, 0, stream>>>(bucketed, gcur, srtbase, srt, row_ptr);
}

extern "C" void kernel_launch(void* const* d_in, const int* in_sizes, int n_in,
                              void* d_out, int out_size, void* d_ws, size_t ws_size,
                              hipStream_t stream) {
    const int*   adj_rows = (const int*)  d_in[0];
    const int*   adj_cols = (const int*)  d_in[1];
    const float* adj_vals = (const float*)d_in[2];
    const float* feat0    = (const float*)d_in[3];
    const float* feat1    = (const float*)d_in[4];
    const float* W1       = (const float*)d_in[5];
    const float* W2       = (const float*)d_in[6];
    const float* W3       = (const float*)d_in[7];
    const float* W4       = (const float*)d_in[8];
    const float* Rg       = (const float*)d_in[9];
    const float* Dl       = (const float*)d_in[10];
    const int*   edges    = (const int*)  d_in[11];
    const int*   rt_k     = (const int*)  d_in[12];
    float* out = (float*)d_out;

    const size_t NH = (size_t)N_NODES * HDIM;       // 3.2M
    float* ws = (float*)d_ws;
    // layout (float offsets):
    f16*      xwh     = (f16*)ws;                     // 4*NH halfs (table / agg / A)
    f16*      h0      = (f16*)(ws + 2 * NH);          // NH halfs
    f16*      h1      = (f16*)(ws + 2 * NH + NH / 2); // NH halfs
    unsigned* srt     = (unsigned*)(ws + 3 * NH);     // 4E u32 (12.8MB)
    int*      row_ptr = (int*)(ws + 3 * NH + 8 * (size_t)E_ADJ); // 4*(N+1)
    int*      gcur    = row_ptr + 4 * NP1 + 60;       // 4*NBUK*SUBS
    int*      srtbase = gcur + 4 * NBUK * SUBS;       // 4*NBUK
    float*    M       = (float*)(srtbase + 4 * NBUK + 32);       // 4096 f
    unsigned long long* bucketed =
        (unsigned long long*)(M + HDIM * HDIM + 64);             // 4*NBUK*BCAP u64 = 38.5MB
    // y aliases bucketed: y live only in stage 1 (after build A, before build B).
    f16* y = (f16*)bucketed;                          // 4*NH halfs = 25.6MB < 38.5MB
    // W fragment tables after bucketed: 81920 f16 = 160KB
    f16* wfrag = (f16*)(bucketed + (size_t)4 * NBUK * BCAP);
    f16* wf1 = wfrag;            // 32768 f16
    f16* wf2 = wfrag + 32768;    // 16384 f16
    f16* wf3 = wfrag + 49152;    // 16384 f16
    f16* wf4 = wfrag + 65536;    // 16384 f16
    // total ~= 26M floats ~= 104 MB (<= R1's proven 128 MB)

    const int* r2 = adj_rows + 4 * (size_t)E_ADJ;
    const int* c2 = adj_cols + 4 * (size_t)E_ADJ;
    const float* v2 = adj_vals + 4 * (size_t)E_ADJ;

    // ---- pre-pack W fragments ----
    pack_wfrag<<<128, 256, 0, stream>>>(W1, FDIM, wf1);
    pack_wfrag<<<64, 256, 0, stream>>>(W2, HDIM, wf2);
    pack_wfrag<<<64, 256, 0, stream>>>(W3, HDIM, wf3);
    pack_wfrag<<<64, 256, 0, stream>>>(W4, HDIM, wf4);

    // ---- CSR for adjacency group A (stages 1 & 2) ----
    build_csr(adj_rows, adj_cols, adj_vals, gcur, srtbase, bucketed, srt, row_ptr, stream);

    // ---- stage 1: transform (MFMA) then aggregate ----
    gemm1_mfma<<<1563, 256, 0, stream>>>(feat0, feat1, wf1, xwh);
    spmm_csr<<<N_NODES, 256, 0, stream>>>(srt, row_ptr, xwh, y);
    combine_kernel<<<(int)(NH / 2 / 256), 256, 0, stream>>>(y, h0, h1);

    // ---- stage 2: aggregate then transform (MFMA) ----
    agg_csr<<<N_NODES, 256, 0, stream>>>(srt, row_ptr, h0, h1, xwh);
    gemm2_mfma<<<1563, 256, 0, stream>>>(xwh, wf2, h0, h1);

    // ---- CSR for adjacency group B (stages 3 & 4) ----
    build_csr(r2, c2, v2, gcur, srtbase, bucketed, srt, row_ptr, stream);

    // ---- stage 3 ----
    agg_csr<<<N_NODES, 256, 0, stream>>>(srt, row_ptr, h0, h1, xwh);
    gemm2_mfma<<<1563, 256, 0, stream>>>(xwh, wf3, h0, h1);

    // ---- stage 4 ----
    agg_csr<<<N_NODES, 256, 0, stream>>>(srt, row_ptr, h0, h1, xwh);
    gemm2_mfma<<<1563, 256, 0, stream>>>(xwh, wf4, h0, h1);

    // ---- decode: M, A = h0@M (fp16, aliases xwh), dot per edge ----
    make_M<<<(HDIM * HDIM + 255) / 256, 256, 0, stream>>>(Rg, Dl, rt_k, M);
    f16* A = xwh;
    h0M_kernel<<<N_NODES / 16, 256, 0, stream>>>(h0, M, A);
    decode<<<E_DEC * 16 / 256, 256, 0, stream>>>(A, h1, edges, out);
}

// Round 26
// 547.016 us; speedup vs baseline: 1.6015x; 1.0037x over previous
//
#include <hip/hip_runtime.h>

#define N_NODES 50000
#define E_ADJ   800000
#define E_DEC   200000
#define FDIM    128
#define HDIM    64
#define NP1     (N_NODES + 1)
#define NBUK    196            // ceil(50000/256) buckets of 256 rows
#define SUBS    32             // sub-counters per bucket (blockIdx & 31)
#define SCAP    192            // per-sub capacity (mean 127.5, +5.7 sigma)
#define BCAP    (SUBS * SCAP)  // 6144 per bucket
#define TILE_E  1024           // edges per part-block (R20 TLP win)
#define EPB     4              // edges per thread
#define NPBLK   782            // ceil(E_ADJ/TILE_E)

typedef _Float16 f16;
typedef __attribute__((ext_vector_type(2))) _Float16 f16x2;
typedef __attribute__((ext_vector_type(4))) _Float16 f16x4;
typedef __attribute__((ext_vector_type(8))) _Float16 f16x8;
typedef __attribute__((ext_vector_type(4))) float f32x4;

__device__ __forceinline__ int   ntl_i(const int* p)   { return __builtin_nontemporal_load(p); }
__device__ __forceinline__ float ntl_f(const float* p) { return __builtin_nontemporal_load(p); }

// ---------------------------------------------------------------------------
// CSR build (R25 config: TILE_E 1024 part, direct-global bucket_sort).
// ---------------------------------------------------------------------------
__global__ void part_kernel(const int* __restrict__ rows,
                            const int* __restrict__ cols,
                            const float* __restrict__ vals,
                            int* __restrict__ gcur,            // [4][NBUK][SUBS]
                            unsigned long long* __restrict__ bucketed)
{
    const int k   = blockIdx.y;
    const int sub = blockIdx.x & (SUBS - 1);
    const int tid = threadIdx.x;
    const long long t0 = (long long)blockIdx.x * TILE_E;

    __shared__ int hist[NBUK];
    __shared__ int cur[NBUK];
    for (int i = tid; i < NBUK; i += 256) hist[i] = 0;
    __syncthreads();

    for (int it = 0; it < EPB; ++it) {
        const long long e = t0 + it * 256 + tid;
        if (e < E_ADJ) {
            const int r = rows[(size_t)k * E_ADJ + e];
            atomicAdd(&hist[r >> 8], 1);
        }
    }
    __syncthreads();

    for (int i = tid; i < NBUK; i += 256)
        cur[i] = (hist[i] > 0) ? atomicAdd(&gcur[(k * NBUK + i) * SUBS + sub], hist[i]) : 0;
    __syncthreads();

    for (int it = 0; it < EPB; ++it) {
        const long long e = t0 + it * 256 + tid;
        if (e < E_ADJ) {
            const int r = rows[(size_t)k * E_ADJ + e];
            const int b = r >> 8;
            const int pos = atomicAdd(&cur[b], 1);
            const int c = ntl_i(&cols[(size_t)k * E_ADJ + e]);
            const float v = ntl_f(&vals[(size_t)k * E_ADJ + e]);
            const unsigned meta = (unsigned)c | ((unsigned)(r & 255) << 16); // col < 65536
            const unsigned long long payload =
                ((unsigned long long)__float_as_uint(v) << 32) | meta;
            bucketed[(size_t)(k * NBUK + b) * BCAP + sub * SCAP + pos] = payload;
        }
    }
}

__global__ void bucket_scan(const int* __restrict__ gcur, int* __restrict__ srtbase)
{
    __shared__ int tot[4 * NBUK];
    for (int i = threadIdx.x; i < 4 * NBUK; i += 256) {
        int t = 0;
#pragma unroll
        for (int s8 = 0; s8 < SUBS; ++s8) t += gcur[i * SUBS + s8];
        tot[i] = t;
    }
    __syncthreads();
    if (threadIdx.x < 4) {
        const int k = threadIdx.x;
        int run = 0;
        for (int b = 0; b < NBUK; ++b) {
            srtbase[k * NBUK + b] = run;
            run += tot[k * NBUK + b];
        }
    }
}

// srt entry: {val_f16 << 16 | col_u16}. Direct global reads (R19 form).
__global__ void bucket_sort(const unsigned long long* __restrict__ bucketed,
                            const int* __restrict__ gcur,      // [4][NBUK][SUBS]
                            const int* __restrict__ srtbase,
                            unsigned* __restrict__ srt,
                            int* __restrict__ row_ptr)
{
    const int b = blockIdx.x, k = blockIdx.y, tid = threadIdx.x;
    const int base = srtbase[k * NBUK + b];
    const unsigned long long* bk = bucketed + (size_t)(k * NBUK + b) * BCAP;

    __shared__ int scnt[SUBS];
    __shared__ int s[256];
    __shared__ int cur[256];
    __shared__ int rcnt[256];
    rcnt[tid] = 0;
    if (tid < SUBS) scnt[tid] = gcur[(k * NBUK + b) * SUBS + tid];
    __syncthreads();

    for (int s8 = 0; s8 < SUBS; ++s8) {
        const int c8 = scnt[s8];
        for (int i = tid; i < c8; i += 256) {
            const unsigned meta = (unsigned)bk[s8 * SCAP + i];
            atomicAdd(&rcnt[(meta >> 16) & 255], 1);
        }
    }
    __syncthreads();

    const int v = rcnt[tid];
    s[tid] = v;
    __syncthreads();
    for (int off = 1; off < 256; off <<= 1) {
        const int t = (tid >= off) ? s[tid - off] : 0;
        __syncthreads();
        s[tid] += t;
        __syncthreads();
    }
    const int excl = s[tid] - v;

    const int n = b * 256 + tid;
    if (n < N_NODES) row_ptr[k * NP1 + n] = base + excl;
    if (b == NBUK - 1 && tid == 0) row_ptr[k * NP1 + N_NODES] = E_ADJ;
    cur[tid] = base + excl;
    __syncthreads();

    for (int s8 = 0; s8 < SUBS; ++s8) {
        const int c8 = scnt[s8];
        for (int i = tid; i < c8; i += 256) {
            const unsigned long long p = bk[s8 * SCAP + i];
            const unsigned meta = (unsigned)p;
            const int rl = (meta >> 16) & 255;
            const int c  = meta & 0xFFFF;
            const float val = __uint_as_float((unsigned)(p >> 32));
            union { f16 h; unsigned short us; } cv;
            cv.h = (f16)val;
            const int pos = atomicAdd(&cur[rl], 1);
            srt[(size_t)k * E_ADJ + pos] = ((unsigned)cv.us << 16) | (unsigned)c;
        }
    }
}

// ---------------------------------------------------------------------------
// R26 quad gather with packed-f16 accumulation: same memory pattern as R16
// (8B f16x4 loads, es=lane>>4, MLP 4), but the 16 scalar f32 fma per 4-edge
// iter become 8 v_pk_fma_f16 and the val broadcast {v,v} is 2 bit-ops from
// the packed meta (no cvt). ~24 vs 32 lane-instrs (R25: VALUBusy 58% =
// issue-bound side of the 67us). f16 accum err ~2e-3 rel; headroom 0.5/2.1.
// Result valid on lanes 0-15 after f32 2-round xor reduce.
// ---------------------------------------------------------------------------
__device__ __forceinline__ void gather_quads(const unsigned* __restrict__ sp,
                                             int s, int en,
                                             const f16* __restrict__ xk,
                                             int lane, float a[4])
{
    const int es = lane >> 4;
    const int hb = (lane & 15) * 4;
    f16x2 acc0 = {(f16)0.f, (f16)0.f};   // h pair {hb, hb+1}
    f16x2 acc1 = {(f16)0.f, (f16)0.f};   // h pair {hb+2, hb+3}

    for (int base = s; base < en; base += 64) {
        const int cnt = min(64, en - base);
        unsigned meta = 0;
        if (lane < cnt) meta = sp[base + lane];
        const int nq = (cnt + 3) >> 2;
        int p = 0;
        for (; p + 4 <= nq; p += 4) {
            unsigned m[4];
#pragma unroll
            for (int u = 0; u < 4; ++u)
                m[u] = __shfl(meta, (p + u) * 4 + es, 64);
            f16x4 g[4];
            f16x2 vv[4];
#pragma unroll
            for (int u = 0; u < 4; ++u) {
                const unsigned vb = (m[u] >> 16) | (m[u] & 0xFFFF0000u); // {v,v}
                vv[u] = __builtin_bit_cast(f16x2, vb);
                g[u] = *(const f16x4*)(xk + (size_t)(m[u] & 0xFFFF) * HDIM + hb);
            }
#pragma unroll
            for (int u = 0; u < 4; ++u) {
                const f16x2 glo = __builtin_shufflevector(g[u], g[u], 0, 1);
                const f16x2 ghi = __builtin_shufflevector(g[u], g[u], 2, 3);
                acc0 += glo * vv[u];     // v_pk_fma_f16
                acc1 += ghi * vv[u];
            }
        }
        for (; p < nq; ++p) {
            const unsigned m = __shfl(meta, p * 4 + es, 64);
            const unsigned vb = (m >> 16) | (m & 0xFFFF0000u);
            const f16x2 vv = __builtin_bit_cast(f16x2, vb);
            const f16x4 g = *(const f16x4*)(xk + (size_t)(m & 0xFFFF) * HDIM + hb);
            const f16x2 glo = __builtin_shufflevector(g, g, 0, 1);
            const f16x2 ghi = __builtin_shufflevector(g, g, 2, 3);
            acc0 += glo * vv;
            acc1 += ghi * vv;
        }
    }
    a[0] += (float)acc0[0];
    a[1] += (float)acc0[1];
    a[2] += (float)acc1[0];
    a[3] += (float)acc1[1];
#pragma unroll
    for (int j = 0; j < 4; ++j) {
        a[j] += __shfl_xor(a[j], 16, 64);
        a[j] += __shfl_xor(a[j], 32, 64);
    }
}

// ---------------------------------------------------------------------------
// W fragment pre-pack for mfma_f32_16x16x32_f16 (R15, unchanged).
// ---------------------------------------------------------------------------
__global__ void pack_wfrag(const float* __restrict__ W, const int K,
                           f16* __restrict__ out)
{
    const int idx = blockIdx.x * 256 + threadIdx.x;
    const int j    = idx & 7;
    const int lane = (idx >> 3) & 63;
    const int kcs  = K >> 5;
    int rest = idx >> 9;
    const int kc  = rest % kcs; rest /= kcs;
    const int nt  = rest & 3;
    const int rel = rest >> 2;
    const int k   = kc * 32 + ((lane >> 4) * 8) + j;
    const int col = nt * 16 + (lane & 15);
    out[idx] = (f16)W[((size_t)rel * K + k) * HDIM + col];
}

// ---------------------------------------------------------------------------
// Stage-1 transform via MFMA (R15, unchanged).
// ---------------------------------------------------------------------------
__global__ void gemm1_mfma(const float* __restrict__ x0,
                           const float* __restrict__ x1,
                           const f16* __restrict__ wf,   // [4][4][4][64][8]
                           f16* __restrict__ xw)         // [4][N][64]
{
    const int wave = threadIdx.x >> 6;   // relation
    const int lane = threadIdx.x & 63;
    const int n0 = blockIdx.x * 32;      // 1563 blocks cover 50016 (guarded)
    const int q = lane >> 4, r16 = lane & 15;

    const float* xr = (wave & 1) ? x1 : x0;

    f16x8 b[4][4];
#pragma unroll
    for (int nt = 0; nt < 4; ++nt)
#pragma unroll
        for (int kc = 0; kc < 4; ++kc)
            b[nt][kc] = *(const f16x8*)(wf + (((size_t)(wave * 4 + nt) * 4 + kc) * 64 + lane) * 8);

    for (int t = 0; t < 2; ++t) {
        const int row = n0 + t * 16 + r16;
        const int rowc = row < N_NODES ? row : N_NODES - 1;
        f16x8 a[4];
#pragma unroll
        for (int kc = 0; kc < 4; ++kc) {
            const float4 lo = *(const float4*)(xr + (size_t)rowc * FDIM + kc * 32 + q * 8);
            const float4 hi = *(const float4*)(xr + (size_t)rowc * FDIM + kc * 32 + q * 8 + 4);
            f16x8 av;
            av[0] = (f16)lo.x; av[1] = (f16)lo.y; av[2] = (f16)lo.z; av[3] = (f16)lo.w;
            av[4] = (f16)hi.x; av[5] = (f16)hi.y; av[6] = (f16)hi.z; av[7] = (f16)hi.w;
            a[kc] = av;
        }
#pragma unroll
        for (int nt = 0; nt < 4; ++nt) {
            f32x4 acc = {0.f, 0.f, 0.f, 0.f};
#pragma unroll
            for (int kc = 0; kc < 4; ++kc)
                acc = __builtin_amdgcn_mfma_f32_16x16x32_f16(a[kc], b[nt][kc], acc, 0, 0, 0);
#pragma unroll
            for (int j = 0; j < 4; ++j) {
                const int n = n0 + t * 16 + q * 4 + j;
                if (n < N_NODES)
                    xw[((size_t)wave * N_NODES + n) * HDIM + nt * 16 + r16] = (f16)acc[j];
            }
        }
    }
}

// ---------------------------------------------------------------------------
// Stages 2-4 transform via MFMA + fused relu + pairwise combine (R15).
// ---------------------------------------------------------------------------
__global__ void gemm2_mfma(const f16* __restrict__ agg,  // [4][N][64]
                           const f16* __restrict__ wf,   // [4][4][2][64][8]
                           f16* __restrict__ h0, f16* __restrict__ h1)
{
    const int wave = threadIdx.x >> 6;
    const int lane = threadIdx.x & 63;
    const int tid  = threadIdx.x;
    const int n0 = blockIdx.x * 32;
    const int q = lane >> 4, r16 = lane & 15;

    f16x8 b[4][2];
#pragma unroll
    for (int nt = 0; nt < 4; ++nt)
#pragma unroll
        for (int kc = 0; kc < 2; ++kc)
            b[nt][kc] = *(const f16x8*)(wf + (((size_t)(wave * 4 + nt) * 2 + kc) * 64 + lane) * 8);

    __shared__ f16 yt[4][16][HDIM];

    for (int t = 0; t < 2; ++t) {
        const int row = n0 + t * 16 + r16;
        const int rowc = row < N_NODES ? row : N_NODES - 1;
        f16x8 a[2];
#pragma unroll
        for (int kc = 0; kc < 2; ++kc)
            a[kc] = *(const f16x8*)(agg + ((size_t)wave * N_NODES + rowc) * HDIM + kc * 32 + q * 8);

#pragma unroll
        for (int nt = 0; nt < 4; ++nt) {
            f32x4 acc = {0.f, 0.f, 0.f, 0.f};
#pragma unroll
            for (int kc = 0; kc < 2; ++kc)
                acc = __builtin_amdgcn_mfma_f32_16x16x32_f16(a[kc], b[nt][kc], acc, 0, 0, 0);
#pragma unroll
            for (int j = 0; j < 4; ++j)
                yt[wave][q * 4 + j][nt * 16 + r16] = (f16)fmaxf(acc[j], 0.f);
        }
        __syncthreads();

        {
            const int r  = tid >> 4;          // 0..15
            const int c4 = (tid & 15) * 4;    // 0..60
            const int n  = n0 + t * 16 + r;
            if (n < N_NODES) {
                const f16x4 a0 = *(const f16x4*)&yt[0][r][c4];
                const f16x4 a1 = *(const f16x4*)&yt[1][r][c4];
                const f16x4 a2 = *(const f16x4*)&yt[2][r][c4];
                const f16x4 a3 = *(const f16x4*)&yt[3][r][c4];
                f16x4 o0, o1;
#pragma unroll
                for (int u = 0; u < 4; ++u) {
                    o0[u] = (f16)((float)a0[u] + (float)a1[u]);
                    o1[u] = (f16)((float)a2[u] + (float)a3[u]);
                }
                *(f16x4*)(h0 + (size_t)n * HDIM + c4) = o0;
                *(f16x4*)(h1 + (size_t)n * HDIM + c4) = o1;
            }
        }
        __syncthreads();
    }
}

// ---------------------------------------------------------------------------
// Stage-1 SPMM, relation-per-block + quad gathers.
// ---------------------------------------------------------------------------
__global__ void spmm_csr(const unsigned* __restrict__ srt,
                         const int*    __restrict__ row_ptr,
                         const f16*    __restrict__ xw,     // [4][N][H]
                         f16* __restrict__ y)               // [4][N][H] relu'd
{
    const int b = blockIdx.x, k = b & 3, g = b >> 2;        // 50000 blocks
    const int wave = threadIdx.x >> 6, lane = threadIdx.x & 63;
    const int n = g * 4 + wave;

    const int s  = row_ptr[k * NP1 + n];
    const int en = row_ptr[k * NP1 + n + 1];
    float a[4] = {0.f, 0.f, 0.f, 0.f};
    gather_quads(srt + (size_t)k * E_ADJ, s, en,
                 xw + (size_t)k * N_NODES * HDIM, lane, a);
    if (lane < 16) {
        f16x4 o;
        o[0] = (f16)fmaxf(a[0], 0.f);
        o[1] = (f16)fmaxf(a[1], 0.f);
        o[2] = (f16)fmaxf(a[2], 0.f);
        o[3] = (f16)fmaxf(a[3], 0.f);
        *(f16x4*)(y + ((size_t)k * N_NODES + n) * HDIM + lane * 4) = o;
    }
}

// h0 = y0+y1, h1 = y2+y3 (y already relu'd per relation).
__global__ void combine_kernel(const f16* __restrict__ y,
                               f16* __restrict__ h0, f16* __restrict__ h1)
{
    const size_t NHh = (size_t)N_NODES * HDIM / 2;
    const size_t i = (size_t)blockIdx.x * 256 + threadIdx.x;   // 6250 blocks exact
    const f16x2 a = ((const f16x2*)y)[i];
    const f16x2 b = ((const f16x2*)y)[NHh + i];
    const f16x2 c = ((const f16x2*)y)[2 * NHh + i];
    const f16x2 d = ((const f16x2*)y)[3 * NHh + i];
    f16x2 o0, o1;
    o0.x = (f16)((float)a.x + (float)b.x);
    o0.y = (f16)((float)a.y + (float)b.y);
    o1.x = (f16)((float)c.x + (float)d.x);
    o1.y = (f16)((float)c.y + (float)d.y);
    ((f16x2*)h0)[i] = o0;
    ((f16x2*)h1)[i] = o1;
}

// ---------------------------------------------------------------------------
// Stages 2-4 aggregate, relation-per-block + quad gathers.
// ---------------------------------------------------------------------------
__global__ void agg_csr(const unsigned* __restrict__ srt,
                        const int*    __restrict__ row_ptr,
                        const f16*    __restrict__ h0,
                        const f16*    __restrict__ h1,
                        f16* __restrict__ agg)    // [4][N][H]
{
    const int b = blockIdx.x, k = b & 3, g = b >> 2;        // 50000 blocks
    const int wave = threadIdx.x >> 6, lane = threadIdx.x & 63;
    const int n = g * 4 + wave;

    const int s  = row_ptr[k * NP1 + n];
    const int en = row_ptr[k * NP1 + n + 1];
    const f16* xk = (k & 1) ? h1 : h0;
    float a[4] = {0.f, 0.f, 0.f, 0.f};
    gather_quads(srt + (size_t)k * E_ADJ, s, en, xk, lane, a);
    if (lane < 16) {
        f16x4 o;
        o[0] = (f16)a[0];
        o[1] = (f16)a[1];
        o[2] = (f16)a[2];
        o[3] = (f16)a[3];
        *(f16x4*)(agg + ((size_t)k * N_NODES + n) * HDIM + lane * 4) = o;
    }
}

// ---------------------------------------------------------------------------
__global__ void make_M(const float* __restrict__ R, const float* __restrict__ Dl,
                       const int* __restrict__ rt_k, float* __restrict__ M)
{
    const int i = blockIdx.x * blockDim.x + threadIdx.x;
    if (i >= HDIM * HDIM) return;
    const float* d = Dl + rt_k[0] * HDIM;
    M[i] = d[i >> 6] * R[i] * d[i & 63];
}

// A[n][g] = sum_h h0[n][h] * M[h][g]   (fp16 out)
__global__ void h0M_kernel(const f16* __restrict__ h0, const float* __restrict__ M,
                           f16* __restrict__ A)
{
    const int wave = threadIdx.x >> 6, lane = threadIdx.x & 63;
    const int n0 = blockIdx.x * 16;      // 3125 blocks

    __shared__ float sx[16][HDIM];
    for (int i = threadIdx.x; i < 16 * HDIM; i += 256)
        sx[i >> 6][i & 63] = (float)h0[(size_t)n0 * HDIM + i];
    __syncthreads();

    float acc[4] = {0.f, 0.f, 0.f, 0.f};
#pragma unroll 4
    for (int f = 0; f < HDIM; ++f) {
        const float w = M[f * HDIM + lane];
#pragma unroll
        for (int r = 0; r < 4; ++r)
            acc[r] = fmaf(sx[wave * 4 + r][f], w, acc[r]);
    }
#pragma unroll
    for (int r = 0; r < 4; ++r)
        A[(size_t)(n0 + wave * 4 + r) * HDIM + lane] = (f16)acc[r];
}

// preds[e] = dot(A[i], h1[j]) — 4 edges/wave, f16x4 (8B) loads.
__global__ void decode(const f16* __restrict__ A, const f16* __restrict__ h1,
                       const int* __restrict__ edges, float* __restrict__ out)
{
    const int w = (blockIdx.x * 256 + threadIdx.x) >> 6;   // 12500 blocks -> 50000 waves
    const int lane = threadIdx.x & 63;
    const int e = w * 4 + (lane >> 4);                     // 4 edges per wave
    const int q = lane & 15;

    const int i = edges[2 * (size_t)e];
    const int j = edges[2 * (size_t)e + 1];

    const f16x4 a = *(const f16x4*)(A + (size_t)i * HDIM + q * 4);
    const f16x4 b = *(const f16x4*)(h1 + (size_t)j * HDIM + q * 4);
    float p = 0.f;
#pragma unroll
    for (int u = 0; u < 4; ++u)
        p = fmaf((float)a[u], (float)b[u], p);
    p += __shfl_xor(p, 1, 64);
    p += __shfl_xor(p, 2, 64);
    p += __shfl_xor(p, 4, 64);
    p += __shfl_xor(p, 8, 64);
    if (q == 0) out[e] = p;
}

// ---------------------------------------------------------------------------
static void build_csr(const int* rows, const int* cols, const float* vals,
                      int* gcur, int* srtbase, unsigned long long* bucketed,
                      unsigned* srt, int* row_ptr, hipStream_t stream)
{
    hipMemsetAsync(gcur, 0, 4 * NBUK * SUBS * sizeof(int), stream);
    part_kernel<<<dim3(NPBLK, 4), 256, 0, stream>>>(rows, cols, vals, gcur, bucketed);
    bucket_scan<<<1, 256, 0, stream>>>(gcur, srtbase);
    bucket_sort<<<dim3(NBUK, 4), 256, 0, stream>>>(bucketed, gcur, srtbase, srt, row_ptr);
}

extern "C" void kernel_launch(void* const* d_in, const int* in_sizes, int n_in,
                              void* d_out, int out_size, void* d_ws, size_t ws_size,
                              hipStream_t stream) {
    const int*   adj_rows = (const int*)  d_in[0];
    const int*   adj_cols = (const int*)  d_in[1];
    const float* adj_vals = (const float*)d_in[2];
    const float* feat0    = (const float*)d_in[3];
    const float* feat1    = (const float*)d_in[4];
    const float* W1       = (const float*)d_in[5];
    const float* W2       = (const float*)d_in[6];
    const float* W3       = (const float*)d_in[7];
    const float* W4       = (const float*)d_in[8];
    const float* Rg       = (const float*)d_in[9];
    const float* Dl       = (const float*)d_in[10];
    const int*   edges    = (const int*)  d_in[11];
    const int*   rt_k     = (const int*)  d_in[12];
    float* out = (float*)d_out;

    const size_t NH = (size_t)N_NODES * HDIM;       // 3.2M
    float* ws = (float*)d_ws;
    // layout (float offsets):
    f16*      xwh     = (f16*)ws;                     // 4*NH halfs (table / agg / A)
    f16*      h0      = (f16*)(ws + 2 * NH);          // NH halfs
    f16*      h1      = (f16*)(ws + 2 * NH + NH / 2); // NH halfs
    unsigned* srt     = (unsigned*)(ws + 3 * NH);     // 4E u32 (12.8MB)
    int*      row_ptr = (int*)(ws + 3 * NH + 8 * (size_t)E_ADJ); // 4*(N+1)
    int*      gcur    = row_ptr + 4 * NP1 + 60;       // 4*NBUK*SUBS
    int*      srtbase = gcur + 4 * NBUK * SUBS;       // 4*NBUK
    float*    M       = (float*)(srtbase + 4 * NBUK + 32);       // 4096 f
    unsigned long long* bucketed =
        (unsigned long long*)(M + HDIM * HDIM + 64);             // 4*NBUK*BCAP u64 = 38.5MB
    // y aliases bucketed: y live only in stage 1 (after build A, before build B).
    f16* y = (f16*)bucketed;                          // 4*NH halfs = 25.6MB < 38.5MB
    // W fragment tables after bucketed: 81920 f16 = 160KB
    f16* wfrag = (f16*)(bucketed + (size_t)4 * NBUK * BCAP);
    f16* wf1 = wfrag;            // 32768 f16
    f16* wf2 = wfrag + 32768;    // 16384 f16
    f16* wf3 = wfrag + 49152;    // 16384 f16
    f16* wf4 = wfrag + 65536;    // 16384 f16
    // total ~= 26M floats ~= 104 MB (<= R1's proven 128 MB)

    const int* r2 = adj_rows + 4 * (size_t)E_ADJ;
    const int* c2 = adj_cols + 4 * (size_t)E_ADJ;
    const float* v2 = adj_vals + 4 * (size_t)E_ADJ;

    // ---- pre-pack W fragments ----
    pack_wfrag<<<128, 256, 0, stream>>>(W1, FDIM, wf1);
    pack_wfrag<<<64, 256, 0, stream>>>(W2, HDIM, wf2);
    pack_wfrag<<<64, 256, 0, stream>>>(W3, HDIM, wf3);
    pack_wfrag<<<64, 256, 0, stream>>>(W4, HDIM, wf4);

    // ---- CSR for adjacency group A (stages 1 & 2) ----
    build_csr(adj_rows, adj_cols, adj_vals, gcur, srtbase, bucketed, srt, row_ptr, stream);

    // ---- stage 1: transform (MFMA) then aggregate ----
    gemm1_mfma<<<1563, 256, 0, stream>>>(feat0, feat1, wf1, xwh);
    spmm_csr<<<N_NODES, 256, 0, stream>>>(srt, row_ptr, xwh, y);
    combine_kernel<<<(int)(NH / 2 / 256), 256, 0, stream>>>(y, h0, h1);

    // ---- stage 2: aggregate then transform (MFMA) ----
    agg_csr<<<N_NODES, 256, 0, stream>>>(srt, row_ptr, h0, h1, xwh);
    gemm2_mfma<<<1563, 256, 0, stream>>>(xwh, wf2, h0, h1);

    // ---- CSR for adjacency group B (stages 3 & 4) ----
    build_csr(r2, c2, v2, gcur, srtbase, bucketed, srt, row_ptr, stream);

    // ---- stage 3 ----
    agg_csr<<<N_NODES, 256, 0, stream>>>(srt, row_ptr, h0, h1, xwh);
    gemm2_mfma<<<1563, 256, 0, stream>>>(xwh, wf3, h0, h1);

    // ---- stage 4 ----
    agg_csr<<<N_NODES, 256, 0, stream>>>(srt, row_ptr, h0, h1, xwh);
    gemm2_mfma<<<1563, 256, 0, stream>>>(xwh, wf4, h0, h1);

    // ---- decode: M, A = h0@M (fp16, aliases xwh), dot per edge ----
    make_M<<<(HDIM * HDIM + 255) / 256, 256, 0, stream>>>(Rg, Dl, rt_k, M);
    f16* A = xwh;
    h0M_kernel<<<N_NODES / 16, 256, 0, stream>>>(h0, M, A);
    decode<<<E_DEC * 16 / 256, 256, 0, stream>>>(A, h1, edges, out);
}